// Round 24
// baseline (71.659 us; speedup 1.0000x reference)
//
#include <hip/hip_runtime.h>

typedef __attribute__((ext_vector_type(8)))  short bf16x8;
typedef __attribute__((ext_vector_type(16))) float f32x16;
typedef __attribute__((ext_vector_type(2)))  float f32x2;

#define KNBR 32
#define WAVES 8         // waves per block (512 threads)
#define QPB  16         // queries per block: wave w -> qa=blk*16+w, qb=qa+8

union Frag { int4 i; bf16x8 b; };

__device__ __forceinline__ unsigned short f2bf(float f) {
    unsigned u = __float_as_uint(f);
    u += 0x7FFFu + ((u >> 16) & 1u);          // RNE to bf16
    return (unsigned short)(u >> 16);
}

__device__ __forceinline__ unsigned cvt_pk_bf16(float lo, float hi) {
    unsigned r;
    asm("v_cvt_pk_bf16_f32 %0, %1, %2" : "=v"(r) : "v"(lo), "v"(hi));
    return r;
}

// gelu_tanh(v) = v * sigmoid(2*c0*(v + c1 v^3)), 2-wide packed (v_pk_* fp32);
// only exp/rcp are scalar trans ops.
__device__ __forceinline__ f32x2 fast_gelu2(f32x2 v) {
    const f32x2 c1v  = {0.044715f, 0.044715f};
    const f32x2 onev = {1.0f, 1.0f};
    const f32x2 K2v  = {-2.3022081951f, -2.3022081951f};  // -2*sqrt(2/pi)*log2(e)
    f32x2 p = v * __builtin_elementwise_fma(c1v, v * v, onev);
    f32x2 t = K2v * p;
    float e0, e1, r0, r1;
    asm("v_exp_f32 %0, %1" : "=v"(e0) : "v"(t.x));
    asm("v_exp_f32 %0, %1" : "=v"(e1) : "v"(t.y));
    f32x2 ev = {e0, e1};
    f32x2 d = ev + onev;
    asm("v_rcp_f32 %0, %1" : "=v"(r0) : "v"(d.x));
    asm("v_rcp_f32 %0, %1" : "=v"(r1) : "v"(d.y));
    f32x2 rv = {r0, r1};
    return v * rv;
}

// One prep kernel: W1/W2/av packing (idx < 2432) + f_y fp32->bf16 (rest).
// 32x32x16 fragment maps (A: row=l&31, B: col=l&31, k=(l>>5)*8+e per K-step).
// C/D: col=lane&31, row=(reg&3)+8*(reg>>2)+4*(lane>>5)  [verified r15].
// GEMM1 slot map (K padded 70->80): 0..63 f_y; 64..69 coords; 70 BIAS; rest 0.
// GEMM2 slot map = identity on h's C/D register layout.
__global__ __launch_bounds__(256) void prep_kernel(
    const float* __restrict__ W1, const float* __restrict__ W2,
    const float* __restrict__ b1, const float* __restrict__ av,
    const float* __restrict__ f_y,
    int4* __restrict__ W1p, int4* __restrict__ W2p, float* __restrict__ avp,
    int4* __restrict__ fyb, int n8)
{
    const int idx = blockIdx.x * 256 + threadIdx.x;
    unsigned short vals[8];
    if (idx < 1280) {                      // W1 A-frags: 20 regions x 64 lanes
        const int a = idx >> 6, l = idx & 63;
        const int Mt = a / 5, ks = a - Mt * 5;
        const int row = Mt * 32 + (l & 31), hi = l >> 5;
        #pragma unroll
        for (int e = 0; e < 8; ++e) {
            const int slot = ks * 16 + hi * 8 + e;
            float f;
            if      (slot < 64)  f = W1[(slot + 6) * 128 + row];
            else if (slot < 70)  f = W1[(slot - 64) * 128 + row];
            else if (slot == 70) f = b1[row];
            else                 f = 0.0f;
            vals[e] = f2bf(f);
        }
        int4 v;
        v.x = vals[0] | (vals[1] << 16); v.y = vals[2] | (vals[3] << 16);
        v.z = vals[4] | (vals[5] << 16); v.w = vals[6] | (vals[7] << 16);
        W1p[idx] = v;
    } else if (idx < 2304) {               // W2 B-frags: 16 regions x 64 lanes
        const int i2 = idx - 1280;
        const int rgn = i2 >> 6, l = i2 & 63;
        const int Nt = rgn >> 3, ks2 = rgn & 7;
        const int col = Nt * 32 + (l & 31), hi = l >> 5;
        #pragma unroll
        for (int e = 0; e < 8; ++e) {
            const int Mt = ks2 >> 1;
            const int t  = 2 * (ks2 & 1) + (e >> 2);
            const int c  = e & 3;
            const int hid = Mt * 32 + 4 * (2 * t + hi) + c;
            vals[e] = f2bf(W2[hid * 64 + col]);
        }
        int4 v;
        v.x = vals[0] | (vals[1] << 16); v.y = vals[2] | (vals[3] << 16);
        v.z = vals[4] | (vals[5] << 16); v.w = vals[6] | (vals[7] << 16);
        W2p[i2] = v;
    } else if (idx < 2432) {               // av repacked into C/D reg order
        const int r_ = idx - 2304;         // [Mt][hi][r]
        const int Mt = r_ >> 5, hi = (r_ >> 4) & 1, r = r_ & 15;
        avp[r_] = av[Mt * 32 + 8 * (r >> 2) + 4 * hi + (r & 3)];
    } else {                               // f_y fp32 -> bf16 (8 f32/thread)
        const int i = idx - 2432;
        if (i < n8) {
            const float4* s = (const float4*)(f_y + (long)i * 8);
            float4 v0 = s[0], v1 = s[1];
            int4 p;
            p.x = cvt_pk_bf16(v0.x, v0.y);
            p.y = cvt_pk_bf16(v0.z, v0.w);
            p.z = cvt_pk_bf16(v1.x, v1.y);
            p.w = cvt_pk_bf16(v1.z, v1.w);
            fyb[i] = p;
        }
    }
}

__global__ __launch_bounds__(512, 4) void it_mfma_kernel(
    const float* __restrict__ y,     // [n_in][3]
    const float* __restrict__ xq,    // [n_out][3]
    const int4*  __restrict__ fyb,   // [n_in] rows of 64 bf16 (8 int4 each)
    const float* __restrict__ b2,    // [64]
    const int*   __restrict__ nbr,   // [n_out*32]
    const int4*  __restrict__ Wall,  // W1p(1280) ++ W2p(1024) ++ avp(128 f32)
    float*       __restrict__ out,   // [n_out][64]
    int n_out)
{
    __shared__ int4  sW[2304];             // 36 KB: W1 frags then W2 frags
    __shared__ float sAv[128];             // av in C/D register order

    const int tid = threadIdx.x;
    const int w   = tid >> 6;              // wave 0..7
    const int l   = tid & 63;              // lane
    const int el  = l & 31;                // this lane's edge
    const int hi  = l >> 5;                // lane half

    const int qa = blockIdx.x * QPB + w;   // wave's first query
    const int qb = qa + WAVES;             // wave's second query (sequential)
    const bool act_a = (qa < n_out);
    const bool act_b = (qb < n_out);
    const int qca = act_a ? qa : 0;
    const int qcb = act_b ? qb : 0;

    // both nbr loads first (coalesced); qa's f_y chain starts ASAP
    const int ni_a = nbr[qca * KNBR + el];
    const int ni_b = nbr[qcb * KNBR + el];

    // ---- stage fragments + av into LDS (issues immediately) ----
    #pragma unroll
    for (int t = 0; t < 5; ++t) {
        const int idx = tid + t * 512;
        if (idx < 2304) sW[idx] = Wall[idx];
    }
    if (tid < 128) sAv[tid] = ((const float*)(Wall + 2304))[tid];

    // ---- query-a gather pre-barrier: hides under staging + barrier ----
    const int4* fb = fyb + (long)ni_a * 8; // 64 bf16 = 8 int4 per row
    int4 g0 = fb[0 + hi], g1 = fb[2 + hi];
    int4 g2 = fb[4 + hi], g3 = fb[6 + hi];
    float2 y01 = {0.f, 0.f}, x01 = {0.f, 0.f};
    float  yz = 0.f, xz = 0.f;
    if (hi == 0) {
        y01 = *(const float2*)(y + ni_a * 3);
        yz  = y[ni_a * 3 + 2];
        x01 = *(const float2*)(xq + qca * 3);
        xz  = xq[qca * 3 + 2];
    }
    __syncthreads();
    const int4* sW1 = sW;                  // region (Mt*5+ks)*64 + lane
    const int4* sW2 = sW + 1280;           // region (Nt*8+ks2)*64 + lane

    if (!act_a) return;                    // after the only barrier: safe

    const f32x16 z16 = {0.f,0.f,0.f,0.f,0.f,0.f,0.f,0.f,
                        0.f,0.f,0.f,0.f,0.f,0.f,0.f,0.f};

    // ---- two queries per wave, strictly sequential (one live state) ----
    #pragma unroll 1
    for (int it = 0; it < 2; ++it) {
        if (it == 1) {
            if (!act_b) return;
            // gather query b fresh (same registers; other waves cover latency)
            const int4* fb2 = fyb + (long)ni_b * 8;
            g0 = fb2[0 + hi]; g1 = fb2[2 + hi];
            g2 = fb2[4 + hi]; g3 = fb2[6 + hi];
            if (hi == 0) {
                y01 = *(const float2*)(y + ni_b * 3);
                yz  = y[ni_b * 3 + 2];
                x01 = *(const float2*)(xq + qcb * 3);
                xz  = xq[qcb * 3 + 2];
            }
        }
        const int qc = (it == 0) ? qca : qcb;

        // ---------- phase 1: B1 fragments ----------
        Frag B1[5];
        B1[0].i = g0; B1[1].i = g1; B1[2].i = g2; B1[3].i = g3;
        B1[4].i = make_int4(0, 0, 0, 0);
        if (hi == 0) {                     // slots 64..71: coords + bias-1.0
            B1[4].i.x = cvt_pk_bf16(y01.x, y01.y);
            B1[4].i.y = cvt_pk_bf16(yz,    x01.x);
            B1[4].i.z = cvt_pk_bf16(x01.y, xz);
            B1[4].i.w = cvt_pk_bf16(1.0f,  0.0f);   // slot 70 = bias edge value
        }

        // ---------- phase 2+3: GEMM1 (Mtile pairs) + packed gelu + score ----
        Frag A2[8];
        f32x2 scv = {0.f, 0.f};
        #pragma unroll
        for (int p = 0; p < 2; ++p) {
            f32x16 aA = z16, aB = z16;
            __builtin_amdgcn_s_setprio(1); // favor this wave's MFMA cluster
            #pragma unroll
            for (int ks = 0; ks < 5; ++ks) {
                Frag wa0, wa1;
                wa0.i = sW1[((2 * p + 0) * 5 + ks) * 64 + l];
                wa1.i = sW1[((2 * p + 1) * 5 + ks) * 64 + l];
                aA = __builtin_amdgcn_mfma_f32_32x32x16_bf16(wa0.b, B1[ks].b, aA, 0, 0, 0);
                aB = __builtin_amdgcn_mfma_f32_32x32x16_bf16(wa1.b, B1[ks].b, aB, 0, 0, 0);
            }
            __builtin_amdgcn_s_setprio(0);
            #pragma unroll
            for (int m = 0; m < 2; ++m) {
                const f32x16 ac = m ? aB : aA;
                const int Mt = 2 * p + m;
                const float* avb = sAv + Mt * 32 + hi * 16;
                float4 av0 = *(const float4*)(avb + 0);
                float4 av1 = *(const float4*)(avb + 4);
                float4 av2 = *(const float4*)(avb + 8);
                float4 av3 = *(const float4*)(avb + 12);
                f32x2 avv[8] = {{av0.x, av0.y}, {av0.z, av0.w},
                                {av1.x, av1.y}, {av1.z, av1.w},
                                {av2.x, av2.y}, {av2.z, av2.w},
                                {av3.x, av3.y}, {av3.z, av3.w}};
                unsigned hw[8];
                #pragma unroll
                for (int i = 0; i < 8; ++i) {
                    f32x2 vin = {ac[2 * i], ac[2 * i + 1]};
                    f32x2 hv = fast_gelu2(vin);
                    scv = __builtin_elementwise_fma(hv, avv[i], scv);
                    hw[i] = cvt_pk_bf16(hv.x, hv.y);
                }
                A2[2 * Mt + 0].i.x = hw[0];
                A2[2 * Mt + 0].i.y = hw[1];
                A2[2 * Mt + 0].i.z = hw[2];
                A2[2 * Mt + 0].i.w = hw[3];
                A2[2 * Mt + 1].i.x = hw[4];
                A2[2 * Mt + 1].i.y = hw[5];
                A2[2 * Mt + 1].i.z = hw[6];
                A2[2 * Mt + 1].i.w = hw[7];
            }
        }

        // ---------- phase 4: softmax (edge el per lane) ----------
        float sc = scv.x + scv.y;
        sc += __shfl_xor(sc, 32, 64);      // sum over lane halves
        float mx = sc;
        mx = fmaxf(mx, __shfl_xor(mx, 1, 64));
        mx = fmaxf(mx, __shfl_xor(mx, 2, 64));
        mx = fmaxf(mx, __shfl_xor(mx, 4, 64));
        mx = fmaxf(mx, __shfl_xor(mx, 8, 64));
        mx = fmaxf(mx, __shfl_xor(mx, 16, 64));
        float ex = __expf(sc - mx);
        float sm = ex;
        sm += __shfl_xor(sm, 1, 64);
        sm += __shfl_xor(sm, 2, 64);
        sm += __shfl_xor(sm, 4, 64);
        sm += __shfl_xor(sm, 8, 64);
        sm += __shfl_xor(sm, 16, 64);
        const float alpha = __fdividef(ex, sm);    // alpha[edge el]

        // ---------- phase 5: GEMM2 (D[edge][out], K=128 over 8 steps) -------
        f32x16 o0 = z16, o1 = z16;
        __builtin_amdgcn_s_setprio(1);
        #pragma unroll
        for (int ks2 = 0; ks2 < 8; ++ks2) {
            Frag w0, w1;
            w0.i = sW2[(0 * 8 + ks2) * 64 + l];
            w1.i = sW2[(1 * 8 + ks2) * 64 + l];
            o0 = __builtin_amdgcn_mfma_f32_32x32x16_bf16(A2[ks2].b, w0.b, o0, 0, 0, 0);
            o1 = __builtin_amdgcn_mfma_f32_32x32x16_bf16(A2[ks2].b, w1.b, o1, 0, 0, 0);
        }
        __builtin_amdgcn_s_setprio(0);

        // ---------- phase 6: alpha-weighted edge reduce + store ----------
        float ar[16];
        #pragma unroll
        for (int r = 0; r < 16; ++r)
            ar[r] = __shfl(alpha, 8 * (r >> 2) + 4 * hi + (r & 3), 64);

        #pragma unroll
        for (int nt = 0; nt < 2; ++nt) {
            const f32x16 oo = nt ? o1 : o0;
            f32x2 acc = {0.f, 0.f};
            #pragma unroll
            for (int i = 0; i < 8; ++i) {
                f32x2 ov = {oo[2 * i], oo[2 * i + 1]};
                f32x2 av2 = {ar[2 * i], ar[2 * i + 1]};
                acc = __builtin_elementwise_fma(ov, av2, acc);
            }
            float o = acc.x + acc.y;
            o += __shfl_xor(o, 32, 64);    // sum the two lane halves' edges
            if (l < 32)
                out[qc * 64 + nt * 32 + l] = o + b2[nt * 32 + l];
        }
    }
}

extern "C" void kernel_launch(void* const* d_in, const int* in_sizes, int n_in,
                              void* d_out, int out_size, void* d_ws, size_t ws_size,
                              hipStream_t stream) {
    const float* y   = (const float*)d_in[0];
    const float* xq  = (const float*)d_in[1];
    const float* f_y = (const float*)d_in[2];
    const float* W1  = (const float*)d_in[3];
    const float* b1  = (const float*)d_in[4];
    const float* W2  = (const float*)d_in[5];
    const float* b2  = (const float*)d_in[6];
    const float* av  = (const float*)d_in[7];
    const int*   nbr = (const int*)d_in[8];
    float* out = (float*)d_out;

    const int n_out = in_sizes[1] / 3;      // x is [n_out][3]
    const int nfy   = in_sizes[2];          // n_in * 64 floats

    int4*  W1p = (int4*)d_ws;               // 1280 frags = 20 KB
    int4*  W2p = W1p + 1280;                // 1024 frags = 16 KB
    float* avp = (float*)(W1p + 2304);      // 128 floats (512 B)
    int4*  fyb = W1p + 2336;                // bf16 f_y: nfy*2 bytes (~3.2 MB)

    const int n8 = nfy / 8;                 // int4-granules of bf16 f_y
    const int prep_blk = (2432 + n8 + 255) / 256;
    prep_kernel<<<prep_blk, 256, 0, stream>>>(W1, W2, b1, av, f_y,
                                              W1p, W2p, avp, fyb, n8);

    const int nblk = (n_out + QPB - 1) / QPB;
    it_mfma_kernel<<<nblk, 512, 0, stream>>>(y, xq, fyb, b2, nbr,
                                             W1p, out, n_out);
}

// Round 25
// 65.442 us; speedup vs baseline: 1.0950x; 1.0950x over previous
//
#include <hip/hip_runtime.h>

typedef __attribute__((ext_vector_type(8)))  short bf16x8;
typedef __attribute__((ext_vector_type(16))) float f32x16;
typedef __attribute__((ext_vector_type(2)))  float f32x2;

#define KNBR 32
#define WAVES 8         // waves per block, one query per wave (512 threads)

union Frag { int4 i; bf16x8 b; };

__device__ __forceinline__ unsigned short f2bf(float f) {
    unsigned u = __float_as_uint(f);
    u += 0x7FFFu + ((u >> 16) & 1u);          // RNE to bf16
    return (unsigned short)(u >> 16);
}

__device__ __forceinline__ unsigned cvt_pk_bf16(float lo, float hi) {
    unsigned r;
    asm("v_cvt_pk_bf16_f32 %0, %1, %2" : "=v"(r) : "v"(lo), "v"(hi));
    return r;
}

// gelu_tanh(v) = v * sigmoid(2*c0*(v + c1 v^3)), 2-wide packed (v_pk_* fp32);
// only exp/rcp are scalar trans ops.
__device__ __forceinline__ f32x2 fast_gelu2(f32x2 v) {
    const f32x2 c1v  = {0.044715f, 0.044715f};
    const f32x2 onev = {1.0f, 1.0f};
    const f32x2 K2v  = {-2.3022081951f, -2.3022081951f};  // -2*sqrt(2/pi)*log2(e)
    f32x2 p = v * __builtin_elementwise_fma(c1v, v * v, onev);
    f32x2 t = K2v * p;
    float e0, e1, r0, r1;
    asm("v_exp_f32 %0, %1" : "=v"(e0) : "v"(t.x));
    asm("v_exp_f32 %0, %1" : "=v"(e1) : "v"(t.y));
    f32x2 ev = {e0, e1};
    f32x2 d = ev + onev;
    asm("v_rcp_f32 %0, %1" : "=v"(r0) : "v"(d.x));
    asm("v_rcp_f32 %0, %1" : "=v"(r1) : "v"(d.y));
    f32x2 rv = {r0, r1};
    return v * rv;
}

// One prep kernel: W1/W2/av packing (idx < 2432) + f_y fp32->bf16 (rest).
// 32x32x16 fragment maps (A: row=l&31, B: col=l&31, k=(l>>5)*8+e per K-step).
// C/D: col=lane&31, row=(reg&3)+8*(reg>>2)+4*(lane>>5)  [verified r15].
// GEMM1 slot map (K padded 70->80): 0..63 f_y; 64..69 coords; 70 BIAS; rest 0.
// GEMM2 slot map = identity on h's C/D register layout.
__global__ __launch_bounds__(256) void prep_kernel(
    const float* __restrict__ W1, const float* __restrict__ W2,
    const float* __restrict__ b1, const float* __restrict__ av,
    const float* __restrict__ f_y,
    int4* __restrict__ W1p, int4* __restrict__ W2p, float* __restrict__ avp,
    int4* __restrict__ fyb, int n8)
{
    const int idx = blockIdx.x * 256 + threadIdx.x;
    unsigned short vals[8];
    if (idx < 1280) {                      // W1 A-frags: 20 regions x 64 lanes
        const int a = idx >> 6, l = idx & 63;
        const int Mt = a / 5, ks = a - Mt * 5;
        const int row = Mt * 32 + (l & 31), hi = l >> 5;
        #pragma unroll
        for (int e = 0; e < 8; ++e) {
            const int slot = ks * 16 + hi * 8 + e;
            float f;
            if      (slot < 64)  f = W1[(slot + 6) * 128 + row];
            else if (slot < 70)  f = W1[(slot - 64) * 128 + row];
            else if (slot == 70) f = b1[row];
            else                 f = 0.0f;
            vals[e] = f2bf(f);
        }
        int4 v;
        v.x = vals[0] | (vals[1] << 16); v.y = vals[2] | (vals[3] << 16);
        v.z = vals[4] | (vals[5] << 16); v.w = vals[6] | (vals[7] << 16);
        W1p[idx] = v;
    } else if (idx < 2304) {               // W2 B-frags: 16 regions x 64 lanes
        const int i2 = idx - 1280;
        const int rgn = i2 >> 6, l = i2 & 63;
        const int Nt = rgn >> 3, ks2 = rgn & 7;
        const int col = Nt * 32 + (l & 31), hi = l >> 5;
        #pragma unroll
        for (int e = 0; e < 8; ++e) {
            const int Mt = ks2 >> 1;
            const int t  = 2 * (ks2 & 1) + (e >> 2);
            const int c  = e & 3;
            const int hid = Mt * 32 + 4 * (2 * t + hi) + c;
            vals[e] = f2bf(W2[hid * 64 + col]);
        }
        int4 v;
        v.x = vals[0] | (vals[1] << 16); v.y = vals[2] | (vals[3] << 16);
        v.z = vals[4] | (vals[5] << 16); v.w = vals[6] | (vals[7] << 16);
        W2p[i2] = v;
    } else if (idx < 2432) {               // av repacked into C/D reg order
        const int r_ = idx - 2304;         // [Mt][hi][r]
        const int Mt = r_ >> 5, hi = (r_ >> 4) & 1, r = r_ & 15;
        avp[r_] = av[Mt * 32 + 8 * (r >> 2) + 4 * hi + (r & 3)];
    } else {                               // f_y fp32 -> bf16 (8 f32/thread)
        const int i = idx - 2432;
        if (i < n8) {
            const float4* s = (const float4*)(f_y + (long)i * 8);
            float4 v0 = s[0], v1 = s[1];
            int4 p;
            p.x = cvt_pk_bf16(v0.x, v0.y);
            p.y = cvt_pk_bf16(v0.z, v0.w);
            p.z = cvt_pk_bf16(v1.x, v1.y);
            p.w = cvt_pk_bf16(v1.z, v1.w);
            fyb[i] = p;
        }
    }
}

__global__ __launch_bounds__(512, 4) void it_mfma_kernel(
    const float* __restrict__ y,     // [n_in][3]
    const float* __restrict__ xq,    // [n_out][3]
    const int4*  __restrict__ fyb,   // [n_in] rows of 64 bf16 (8 int4 each)
    const float* __restrict__ b2,    // [64]
    const int*   __restrict__ nbr,   // [n_out*32]
    const int4*  __restrict__ Wall,  // W1p(1280) ++ W2p(1024) ++ avp(128 f32)
    float*       __restrict__ out,   // [n_out][64]
    int n_out)
{
    __shared__ int4  sW[2304];             // 36 KB: W1 frags then W2 frags
    __shared__ float sAv[128];             // av in C/D register order

    const int tid = threadIdx.x;
    const int w   = tid >> 6;              // wave 0..7
    const int l   = tid & 63;              // lane
    const int el  = l & 31;                // this lane's edge
    const int hi  = l >> 5;                // lane half

    const int q = blockIdx.x * WAVES + w;
    const bool active = (q < n_out);
    const int qc = active ? q : 0;

    // nbr first: its latency hides under the (independent) staging loads
    const int ni = nbr[qc * KNBR + el];

    // ---- stage fragments + av into LDS (issues immediately) ----
    #pragma unroll
    for (int t = 0; t < 5; ++t) {
        const int idx = tid + t * 512;
        if (idx < 2304) sW[idx] = Wall[idx];
    }
    if (tid < 128) sAv[tid] = ((const float*)(Wall + 2304))[tid];

    // ---- bf16 f_y gather issues BEFORE the barrier: 4 direct int4 loads,
    //      L2-resident table, already in fragment byte order ----
    const int4* fb = fyb + (long)ni * 8;   // 64 bf16 = 8 int4 per row
    Frag B1[5];
    B1[0].i = fb[0 + hi];                  // slots 16*ks + 8*hi + e
    B1[1].i = fb[2 + hi];
    B1[2].i = fb[4 + hi];
    B1[3].i = fb[6 + hi];
    float2 y01 = {0.f, 0.f}, x01 = {0.f, 0.f};
    float  yz = 0.f, xz = 0.f;
    if (hi == 0) {
        y01 = *(const float2*)(y + ni * 3);
        yz  = y[ni * 3 + 2];
        x01 = *(const float2*)(xq + qc * 3);
        xz  = xq[qc * 3 + 2];
    }
    __syncthreads();
    const int4* sW1 = sW;                  // region (Mt*5+ks)*64 + lane
    const int4* sW2 = sW + 1280;           // region (Nt*8+ks2)*64 + lane

    if (!active) return;                   // after the only barrier: safe

    // ---------- phase 1 tail: coord/bias fragment ----------
    B1[4].i = make_int4(0, 0, 0, 0);
    if (hi == 0) {                         // slots 64..71: coords + bias-1.0
        B1[4].i.x = cvt_pk_bf16(y01.x, y01.y);
        B1[4].i.y = cvt_pk_bf16(yz,    x01.x);
        B1[4].i.z = cvt_pk_bf16(x01.y, xz);
        B1[4].i.w = cvt_pk_bf16(1.0f,  0.0f);   // slot 70 = bias edge value
    }

    const f32x16 z16 = {0.f,0.f,0.f,0.f,0.f,0.f,0.f,0.f,
                        0.f,0.f,0.f,0.f,0.f,0.f,0.f,0.f};

    // ---------- phase 2+3: GEMM1 (Mtile pairs) + packed gelu + score + A2 ---
    Frag A2[8];
    f32x2 scv = {0.f, 0.f};
    #pragma unroll
    for (int p = 0; p < 2; ++p) {
        f32x16 aA = z16, aB = z16;
        __builtin_amdgcn_s_setprio(1);     // favor this wave's MFMA cluster
        #pragma unroll
        for (int ks = 0; ks < 5; ++ks) {
            Frag wa0, wa1;
            wa0.i = sW1[((2 * p + 0) * 5 + ks) * 64 + l];
            wa1.i = sW1[((2 * p + 1) * 5 + ks) * 64 + l];
            aA = __builtin_amdgcn_mfma_f32_32x32x16_bf16(wa0.b, B1[ks].b, aA, 0, 0, 0);
            aB = __builtin_amdgcn_mfma_f32_32x32x16_bf16(wa1.b, B1[ks].b, aB, 0, 0, 0);
        }
        __builtin_amdgcn_s_setprio(0);
        #pragma unroll
        for (int m = 0; m < 2; ++m) {
            const f32x16 ac = m ? aB : aA;
            const int Mt = 2 * p + m;
            const float* avb = sAv + Mt * 32 + hi * 16;
            float4 av0 = *(const float4*)(avb + 0);
            float4 av1 = *(const float4*)(avb + 4);
            float4 av2 = *(const float4*)(avb + 8);
            float4 av3 = *(const float4*)(avb + 12);
            f32x2 avv[8] = {{av0.x, av0.y}, {av0.z, av0.w},
                            {av1.x, av1.y}, {av1.z, av1.w},
                            {av2.x, av2.y}, {av2.z, av2.w},
                            {av3.x, av3.y}, {av3.z, av3.w}};
            unsigned hw[8];
            #pragma unroll
            for (int i = 0; i < 8; ++i) {
                f32x2 vin = {ac[2 * i], ac[2 * i + 1]};
                f32x2 hv = fast_gelu2(vin);
                scv = __builtin_elementwise_fma(hv, avv[i], scv);
                hw[i] = cvt_pk_bf16(hv.x, hv.y);
            }
            A2[2 * Mt + 0].i.x = hw[0];
            A2[2 * Mt + 0].i.y = hw[1];
            A2[2 * Mt + 0].i.z = hw[2];
            A2[2 * Mt + 0].i.w = hw[3];
            A2[2 * Mt + 1].i.x = hw[4];
            A2[2 * Mt + 1].i.y = hw[5];
            A2[2 * Mt + 1].i.z = hw[6];
            A2[2 * Mt + 1].i.w = hw[7];
        }
    }

    // ---- prefetch Nt=0 W2 fragments: LDS latency hides under softmax ----
    Frag wf[8];
    #pragma unroll
    for (int ks2 = 0; ks2 < 8; ++ks2)
        wf[ks2].i = sW2[(0 * 8 + ks2) * 64 + l];

    // ---------- phase 4: softmax (edge el per lane) ----------
    float sc = scv.x + scv.y;
    sc += __shfl_xor(sc, 32, 64);          // sum over lane halves (hidden split)
    float mx = sc;
    mx = fmaxf(mx, __shfl_xor(mx, 1, 64));
    mx = fmaxf(mx, __shfl_xor(mx, 2, 64));
    mx = fmaxf(mx, __shfl_xor(mx, 4, 64));
    mx = fmaxf(mx, __shfl_xor(mx, 8, 64));
    mx = fmaxf(mx, __shfl_xor(mx, 16, 64));
    float ex = __expf(sc - mx);
    float sm = ex;
    sm += __shfl_xor(sm, 1, 64);
    sm += __shfl_xor(sm, 2, 64);
    sm += __shfl_xor(sm, 4, 64);
    sm += __shfl_xor(sm, 8, 64);
    sm += __shfl_xor(sm, 16, 64);
    const float alpha = __fdividef(ex, sm);    // alpha[edge el]

    // ---------- phase 5: GEMM2 (D[edge][out], K=128 over 8 steps) ----------
    f32x16 o0 = z16, o1 = z16;
    __builtin_amdgcn_s_setprio(1);         // favor this wave's MFMA cluster
    #pragma unroll
    for (int ks2 = 0; ks2 < 8; ++ks2) {
        Frag w1;
        w1.i = sW2[(1 * 8 + ks2) * 64 + l];
        o0 = __builtin_amdgcn_mfma_f32_32x32x16_bf16(A2[ks2].b, wf[ks2].b, o0, 0, 0, 0);
        o1 = __builtin_amdgcn_mfma_f32_32x32x16_bf16(A2[ks2].b, w1.b, o1, 0, 0, 0);
    }
    __builtin_amdgcn_s_setprio(0);

    // ---------- phase 6: alpha-weighted edge reduce + store ----------
    float ar[16];
    #pragma unroll
    for (int r = 0; r < 16; ++r)
        ar[r] = __shfl(alpha, 8 * (r >> 2) + 4 * hi + (r & 3), 64);

    #pragma unroll
    for (int nt = 0; nt < 2; ++nt) {
        const f32x16 oo = nt ? o1 : o0;
        f32x2 acc = {0.f, 0.f};
        #pragma unroll
        for (int i = 0; i < 8; ++i) {
            f32x2 ov = {oo[2 * i], oo[2 * i + 1]};
            f32x2 av2 = {ar[2 * i], ar[2 * i + 1]};
            acc = __builtin_elementwise_fma(ov, av2, acc);
        }
        float o = acc.x + acc.y;
        o += __shfl_xor(o, 32, 64);        // sum the two lane halves' edges
        if (l < 32)
            out[qc * 64 + nt * 32 + l] = o + b2[nt * 32 + l];
    }
}

extern "C" void kernel_launch(void* const* d_in, const int* in_sizes, int n_in,
                              void* d_out, int out_size, void* d_ws, size_t ws_size,
                              hipStream_t stream) {
    const float* y   = (const float*)d_in[0];
    const float* xq  = (const float*)d_in[1];
    const float* f_y = (const float*)d_in[2];
    const float* W1  = (const float*)d_in[3];
    const float* b1  = (const float*)d_in[4];
    const float* W2  = (const float*)d_in[5];
    const float* b2  = (const float*)d_in[6];
    const float* av  = (const float*)d_in[7];
    const int*   nbr = (const int*)d_in[8];
    float* out = (float*)d_out;

    const int n_out = in_sizes[1] / 3;      // x is [n_out][3]
    const int nfy   = in_sizes[2];          // n_in * 64 floats

    int4*  W1p = (int4*)d_ws;               // 1280 frags = 20 KB
    int4*  W2p = W1p + 1280;                // 1024 frags = 16 KB
    float* avp = (float*)(W1p + 2304);      // 128 floats (512 B)
    int4*  fyb = W1p + 2336;                // bf16 f_y: nfy*2 bytes (~3.2 MB)

    const int n8 = nfy / 8;                 // int4-granules of bf16 f_y
    const int prep_blk = (2432 + n8 + 255) / 256;
    prep_kernel<<<prep_blk, 256, 0, stream>>>(W1, W2, b1, av, f_y,
                                              W1p, W2p, avp, fyb, n8);

    const int nblk = (n_out + WAVES - 1) / WAVES;
    it_mfma_kernel<<<nblk, 512, 0, stream>>>(y, xq, fyb, b2, nbr,
                                             W1p, out, n_out);
}